// Round 24
// baseline (169.464 us; speedup 1.0000x reference)
//
#include <hip/hip_runtime.h>
#include <hip/hip_bf16.h>
#include <hip/hip_fp8.h>
#include <math.h>

typedef long long i64;
typedef __attribute__((ext_vector_type(8))) short short8v;
typedef __attribute__((ext_vector_type(4))) float f32x4;

__device__ __forceinline__ float bfu(unsigned short u) {
    union { unsigned int i; float f; } v; v.i = ((unsigned)u) << 16; return v.f;
}
__device__ __forceinline__ unsigned short f2b(float f) {
    __hip_bfloat16 h = __float2bfloat16(f);
    return *reinterpret_cast<unsigned short*>(&h);
}
__device__ __forceinline__ float f8u(unsigned char u) {
    __hip_fp8_e4m3 h; h.__x = u; return (float)h;
}
__device__ __forceinline__ unsigned char f2f8(float f) {
    __hip_fp8_e4m3 h(f); return h.__x;
}

// ================= CSR build: 2-phase radix partition by dst =================
// pairs packed: src (bits 0-16) | dst-local (bits 17-25)  [4B/edge]
#define NPB_SHIFT 9
#define NPB 512
#define LCAP 16384
#define P1C 8192

__global__ void k_zeroB(int* __restrict__ bcnt, int B) {
    int t = threadIdx.x;
    if (t <= B) bcnt[t] = 0;
}

__global__ __launch_bounds__(256) void k_p1count(
    const int* __restrict__ dst, int E, int B, int* __restrict__ bcnt) {
    __shared__ int lb[256];
    int t = threadIdx.x;
    lb[t] = 0; __syncthreads();
    int cpb = (E + gridDim.x - 1) / gridDim.x;
    int s0 = blockIdx.x * cpb, s1 = min(E, s0 + cpb);
    for (int i = s0 + t; i < s1; i += 256)
        atomicAdd(&lb[dst[i] >> NPB_SHIFT], 1);
    __syncthreads();
    if (t < B && lb[t]) atomicAdd(&bcnt[t], lb[t]);
}

__global__ void k_scanB(const int* __restrict__ bcnt, int B, int E,
                        int* __restrict__ bstart, int* __restrict__ cursor) {
    __shared__ int s[256];
    int t = threadIdx.x;
    int v = (t < B) ? bcnt[t] : 0;
    s[t] = v; __syncthreads();
    for (int off = 1; off < 256; off <<= 1) {
        int u = (t >= off) ? s[t - off] : 0;
        __syncthreads();
        s[t] += u;
        __syncthreads();
    }
    int excl = s[t] - v;
    if (t < B) { bstart[t] = excl; cursor[t] = excl; }
    if (t == 0) bstart[B] = E;
}

__global__ __launch_bounds__(256) void k_p1place(
    const int* __restrict__ src, const int* __restrict__ dst, int E, int B,
    int* __restrict__ cursor, unsigned* __restrict__ pairs) {
    __shared__ unsigned ls_p[P1C];
    __shared__ unsigned char ls_b[P1C];
    __shared__ int lb[256];
    __shared__ int lbase[256];
    int t = threadIdx.x;
    int s0 = blockIdx.x * P1C, s1 = min(E, s0 + P1C), n = s1 - s0;
    lb[t] = 0; __syncthreads();
    for (int i = t; i < n; i += 256) {
        int d = dst[s0 + i];
        int s = src[s0 + i];
        int bkt = d >> NPB_SHIFT;
        ls_p[i] = (unsigned)s | ((unsigned)(d & (NPB - 1)) << 17);
        ls_b[i] = (unsigned char)bkt;
        atomicAdd(&lb[bkt], 1);
    }
    __syncthreads();
    if (t < B && lb[t]) lbase[t] = atomicAdd(&cursor[t], lb[t]);
    __syncthreads();
    lb[t] = 0; __syncthreads();
    for (int i = t; i < n; i += 256) {
        int bkt = ls_b[i];
        int slot = atomicAdd(&lb[bkt], 1);
        pairs[lbase[bkt] + slot] = ls_p[i];
    }
}

__global__ __launch_bounds__(512) void k_p2(
    const unsigned* __restrict__ pairs, const int* __restrict__ bstart,
    int* __restrict__ rowptr, float* __restrict__ dinv,
    int* __restrict__ col, int N, int E) {
    __shared__ int lcnt[NPB];
    __shared__ int lscan[NPB];
    __shared__ int lcol[LCAP];
    int b = blockIdx.x, t = threadIdx.x;
    int lo = b << NPB_SHIFT, hi = min(N, lo + NPB), nn = hi - lo;
    int e0 = bstart[b], e1 = bstart[b + 1];
    lcnt[t] = 0; __syncthreads();
    for (int i = e0 + t; i < e1; i += 512)
        atomicAdd(&lcnt[(int)(pairs[i] >> 17)], 1);
    __syncthreads();
    int myc = (t < nn) ? lcnt[t] : 0;
    lscan[t] = myc; __syncthreads();
    for (int off = 1; off < 512; off <<= 1) {
        int u = (t >= off) ? lscan[t - off] : 0;
        __syncthreads();
        lscan[t] += u;
        __syncthreads();
    }
    if (t < nn) {
        rowptr[lo + t] = e0 + lscan[t] - myc;
        dinv[lo + t] = rsqrtf((float)(myc + 1));   // +1 self-loop
    }
    if (t == 0 && hi == N) rowptr[N] = E;
    __syncthreads();
    lscan[t] -= myc;
    lcnt[t] = 0;
    __syncthreads();
    for (int i = e0 + t; i < e1; i += 512) {
        unsigned p = pairs[i];
        int n = (int)(p >> 17);
        int slot = atomicAdd(&lcnt[n], 1);
        int idx = lscan[n] + slot;
        if (idx < LCAP) lcol[idx] = (int)(p & 0x1FFFFu);
    }
    __syncthreads();
    int cnt = e1 - e0;
    for (int i = t; i < cnt; i += 512) col[e0 + i] = lcol[i];
}

// ------- GEMM1 (MFMA bf16): g1[r][c] = fp8e4m3( dinv[r] * (x @ W1)[r][c] ) -------

__global__ __launch_bounds__(256) void k_gemm1m(
    const float* __restrict__ X, const float* __restrict__ W,
    const float* __restrict__ dinv, unsigned char* __restrict__ out, int N) {
    __shared__ unsigned short Xs[128 * 128];   // 32 KB
    __shared__ unsigned short Wt[64 * 128];    // 16 KB (W^T)
    int tid = threadIdx.x;
    int row0 = blockIdx.x << 7;

    for (int i = tid; i < 2048; i += 256) {
        float4 v = *(const float4*)(W + i * 4);
        int k = (i * 4) >> 6, n = (i * 4) & 63;
        int kb = k * 2;
        *(unsigned short*)((char*)Wt + (n + 0) * 256 + (kb ^ (((n + 0) & 7) << 4))) = f2b(v.x);
        *(unsigned short*)((char*)Wt + (n + 1) * 256 + (kb ^ (((n + 1) & 7) << 4))) = f2b(v.y);
        *(unsigned short*)((char*)Wt + (n + 2) * 256 + (kb ^ (((n + 2) & 7) << 4))) = f2b(v.z);
        *(unsigned short*)((char*)Wt + (n + 3) * 256 + (kb ^ (((n + 3) & 7) << 4))) = f2b(v.w);
    }
    for (int i = tid; i < 4096; i += 256) {
        int r = i >> 5, c4 = i & 31;
        int gr = row0 + r;
        float4 v = make_float4(0.f, 0.f, 0.f, 0.f);
        if (gr < N) v = *(const float4*)(X + (size_t)gr * 128 + c4 * 4);
        ushort4 h;
        h.x = f2b(v.x); h.y = f2b(v.y); h.z = f2b(v.z); h.w = f2b(v.w);
        *(ushort4*)((char*)Xs + r * 256 + ((c4 * 8) ^ ((r & 7) << 4))) = h;
    }
    __syncthreads();

    int wid = tid >> 6, lane = tid & 63;
    int l15 = lane & 15, lg = lane >> 4;
    int wrow = wid * 32;

    f32x4 acc[2][4];
    #pragma unroll
    for (int fr = 0; fr < 2; fr++)
        #pragma unroll
        for (int fc = 0; fc < 4; fc++) acc[fr][fc] = (f32x4){0.f, 0.f, 0.f, 0.f};

    #pragma unroll
    for (int ks = 0; ks < 4; ks++) {
        int kbyte = ks * 64 + lg * 16;
        int ra0 = wrow + l15, ra1 = wrow + 16 + l15;
        short8v a0 = *(short8v*)((char*)Xs + ra0 * 256 + (kbyte ^ ((ra0 & 7) << 4)));
        short8v a1 = *(short8v*)((char*)Xs + ra1 * 256 + (kbyte ^ ((ra1 & 7) << 4)));
        int swb = kbyte ^ ((l15 & 7) << 4);
        short8v b0 = *(short8v*)((char*)Wt + (l15) * 256 + swb);
        short8v b1 = *(short8v*)((char*)Wt + (16 + l15) * 256 + swb);
        short8v b2 = *(short8v*)((char*)Wt + (32 + l15) * 256 + swb);
        short8v b3 = *(short8v*)((char*)Wt + (48 + l15) * 256 + swb);
        acc[0][0] = __builtin_amdgcn_mfma_f32_16x16x32_bf16(a0, b0, acc[0][0], 0, 0, 0);
        acc[0][1] = __builtin_amdgcn_mfma_f32_16x16x32_bf16(a0, b1, acc[0][1], 0, 0, 0);
        acc[0][2] = __builtin_amdgcn_mfma_f32_16x16x32_bf16(a0, b2, acc[0][2], 0, 0, 0);
        acc[0][3] = __builtin_amdgcn_mfma_f32_16x16x32_bf16(a0, b3, acc[0][3], 0, 0, 0);
        acc[1][0] = __builtin_amdgcn_mfma_f32_16x16x32_bf16(a1, b0, acc[1][0], 0, 0, 0);
        acc[1][1] = __builtin_amdgcn_mfma_f32_16x16x32_bf16(a1, b1, acc[1][1], 0, 0, 0);
        acc[1][2] = __builtin_amdgcn_mfma_f32_16x16x32_bf16(a1, b2, acc[1][2], 0, 0, 0);
        acc[1][3] = __builtin_amdgcn_mfma_f32_16x16x32_bf16(a1, b3, acc[1][3], 0, 0, 0);
    }

    float dv[2][4];
    #pragma unroll
    for (int fr = 0; fr < 2; fr++)
        #pragma unroll
        for (int reg = 0; reg < 4; reg++) {
            int grow = row0 + wrow + fr * 16 + lg * 4 + reg;
            dv[fr][reg] = (grow < N) ? dinv[grow] : 0.f;
        }
    #pragma unroll
    for (int fr = 0; fr < 2; fr++)
        #pragma unroll
        for (int fc = 0; fc < 4; fc++)
            #pragma unroll
            for (int reg = 0; reg < 4; reg++) {
                int grow = row0 + wrow + fr * 16 + lg * 4 + reg;
                if (grow < N)
                    out[(size_t)grow * 64 + fc * 16 + l15] = f2f8(acc[fr][fc][reg] * dv[fr][reg]);
            }
}

// ---- Agg layer 1: fp8 gather, 8 nodes/wave (8 lanes x uint2(8B) = one 64B row).
//      One gather instr = 8 rows = 512B. q written fp8. ----

__global__ __launch_bounds__(256) void k_agg1f8(
    const unsigned char* __restrict__ gsrc, const int* __restrict__ rowptr,
    const int* __restrict__ col, const float* __restrict__ dinv,
    const float* __restrict__ b1, unsigned char* __restrict__ gout, int N) {
    int gw = (int)((blockIdx.x * 256u + threadIdx.x) >> 6);
    int lane = threadIdx.x & 63;
    int li = lane & 7;                          // feature eighth: 8li..8li+7
    int node = gw * 8 + (lane >> 3);
    bool valid = node < N;
    int r0 = 0, r1 = 0;
    if (valid) { r0 = rowptr[node]; r1 = rowptr[node + 1]; }
    size_t fo = (size_t)(li * 8);
    float s[8] = {0.f,0.f,0.f,0.f,0.f,0.f,0.f,0.f};
    if (valid) {   // self-loop term
        uint2 u = *(const uint2*)(gsrc + (((size_t)node) << 6) + fo);
        s[0]+=f8u(u.x&255); s[1]+=f8u((u.x>>8)&255); s[2]+=f8u((u.x>>16)&255); s[3]+=f8u(u.x>>24);
        s[4]+=f8u(u.y&255); s[5]+=f8u((u.y>>8)&255); s[6]+=f8u((u.y>>16)&255); s[7]+=f8u(u.y>>24);
    }
    int e = r0;
    for (; e + 16 <= r1; e += 16) {
        int cc[16];
        #pragma unroll
        for (int j = 0; j < 16; j++) cc[j] = col[e + j];
        uint2 uu[16];
        #pragma unroll
        for (int j = 0; j < 16; j++)
            uu[j] = *(const uint2*)(gsrc + (((size_t)cc[j]) << 6) + fo);
        float a0[8] = {0.f,0.f,0.f,0.f,0.f,0.f,0.f,0.f};
        float a1[8] = {0.f,0.f,0.f,0.f,0.f,0.f,0.f,0.f};
        #pragma unroll
        for (int j = 0; j < 16; j += 2) {
            unsigned x0 = uu[j].x,   y0 = uu[j].y;
            unsigned x1 = uu[j+1].x, y1 = uu[j+1].y;
            a0[0]+=f8u(x0&255); a0[1]+=f8u((x0>>8)&255); a0[2]+=f8u((x0>>16)&255); a0[3]+=f8u(x0>>24);
            a0[4]+=f8u(y0&255); a0[5]+=f8u((y0>>8)&255); a0[6]+=f8u((y0>>16)&255); a0[7]+=f8u(y0>>24);
            a1[0]+=f8u(x1&255); a1[1]+=f8u((x1>>8)&255); a1[2]+=f8u((x1>>16)&255); a1[3]+=f8u(x1>>24);
            a1[4]+=f8u(y1&255); a1[5]+=f8u((y1>>8)&255); a1[6]+=f8u((y1>>16)&255); a1[7]+=f8u(y1>>24);
        }
        #pragma unroll
        for (int k = 0; k < 8; k++) s[k] += a0[k] + a1[k];
    }
    for (; e + 4 <= r1; e += 4) {
        int c0 = col[e], c1 = col[e + 1], c2 = col[e + 2], c3 = col[e + 3];
        uint2 u0 = *(const uint2*)(gsrc + (((size_t)c0) << 6) + fo);
        uint2 u1 = *(const uint2*)(gsrc + (((size_t)c1) << 6) + fo);
        uint2 u2 = *(const uint2*)(gsrc + (((size_t)c2) << 6) + fo);
        uint2 u3 = *(const uint2*)(gsrc + (((size_t)c3) << 6) + fo);
        #pragma unroll
        for (int k = 0; k < 4; k++) {
            int sh = k * 8;
            s[k]     += (f8u((u0.x>>sh)&255) + f8u((u1.x>>sh)&255)) + (f8u((u2.x>>sh)&255) + f8u((u3.x>>sh)&255));
            s[k + 4] += (f8u((u0.y>>sh)&255) + f8u((u1.y>>sh)&255)) + (f8u((u2.y>>sh)&255) + f8u((u3.y>>sh)&255));
        }
    }
    for (; e < r1; ++e) {
        uint2 u = *(const uint2*)(gsrc + (((size_t)col[e]) << 6) + fo);
        s[0]+=f8u(u.x&255); s[1]+=f8u((u.x>>8)&255); s[2]+=f8u((u.x>>16)&255); s[3]+=f8u(u.x>>24);
        s[4]+=f8u(u.y&255); s[5]+=f8u((u.y>>8)&255); s[6]+=f8u((u.y>>16)&255); s[7]+=f8u(u.y>>24);
    }
    if (valid) {
        float dvn = dinv[node];
        float4 ba = *(const float4*)(b1 + li * 8);
        float4 bb = *(const float4*)(b1 + li * 8 + 4);
        unsigned char o[8];
        o[0] = f2f8(dvn * fmaxf(dvn * s[0] + ba.x, 0.f));
        o[1] = f2f8(dvn * fmaxf(dvn * s[1] + ba.y, 0.f));
        o[2] = f2f8(dvn * fmaxf(dvn * s[2] + ba.z, 0.f));
        o[3] = f2f8(dvn * fmaxf(dvn * s[3] + ba.w, 0.f));
        o[4] = f2f8(dvn * fmaxf(dvn * s[4] + bb.x, 0.f));
        o[5] = f2f8(dvn * fmaxf(dvn * s[5] + bb.y, 0.f));
        o[6] = f2f8(dvn * fmaxf(dvn * s[6] + bb.z, 0.f));
        o[7] = f2f8(dvn * fmaxf(dvn * s[7] + bb.w, 0.f));
        uint2 w;
        w.x = (unsigned)o[0] | ((unsigned)o[1] << 8) | ((unsigned)o[2] << 16) | ((unsigned)o[3] << 24);
        w.y = (unsigned)o[4] | ((unsigned)o[5] << 8) | ((unsigned)o[6] << 16) | ((unsigned)o[7] << 24);
        *(uint2*)(gout + (((size_t)node) << 6) + fo) = w;
    }
}

// ---- Agg layer 2: fp8 gather of q, 8 nodes/wave; t output bf16 (16B/lane) ----

__global__ __launch_bounds__(256) void k_agg2f8(
    const unsigned char* __restrict__ gsrc, const int* __restrict__ rowptr,
    const int* __restrict__ col, const float* __restrict__ dinv,
    unsigned short* __restrict__ gout, int N) {
    int gw = (int)((blockIdx.x * 256u + threadIdx.x) >> 6);
    int lane = threadIdx.x & 63;
    int li = lane & 7;
    int node = gw * 8 + (lane >> 3);
    bool valid = node < N;
    int r0 = 0, r1 = 0;
    if (valid) { r0 = rowptr[node]; r1 = rowptr[node + 1]; }
    size_t fo = (size_t)(li * 8);
    float s[8] = {0.f,0.f,0.f,0.f,0.f,0.f,0.f,0.f};
    if (valid) {   // self-loop term
        uint2 u = *(const uint2*)(gsrc + (((size_t)node) << 6) + fo);
        s[0]+=f8u(u.x&255); s[1]+=f8u((u.x>>8)&255); s[2]+=f8u((u.x>>16)&255); s[3]+=f8u(u.x>>24);
        s[4]+=f8u(u.y&255); s[5]+=f8u((u.y>>8)&255); s[6]+=f8u((u.y>>16)&255); s[7]+=f8u(u.y>>24);
    }
    int e = r0;
    for (; e + 16 <= r1; e += 16) {
        int cc[16];
        #pragma unroll
        for (int j = 0; j < 16; j++) cc[j] = col[e + j];
        uint2 uu[16];
        #pragma unroll
        for (int j = 0; j < 16; j++)
            uu[j] = *(const uint2*)(gsrc + (((size_t)cc[j]) << 6) + fo);
        float a0[8] = {0.f,0.f,0.f,0.f,0.f,0.f,0.f,0.f};
        float a1[8] = {0.f,0.f,0.f,0.f,0.f,0.f,0.f,0.f};
        #pragma unroll
        for (int j = 0; j < 16; j += 2) {
            unsigned x0 = uu[j].x,   y0 = uu[j].y;
            unsigned x1 = uu[j+1].x, y1 = uu[j+1].y;
            a0[0]+=f8u(x0&255); a0[1]+=f8u((x0>>8)&255); a0[2]+=f8u((x0>>16)&255); a0[3]+=f8u(x0>>24);
            a0[4]+=f8u(y0&255); a0[5]+=f8u((y0>>8)&255); a0[6]+=f8u((y0>>16)&255); a0[7]+=f8u(y0>>24);
            a1[0]+=f8u(x1&255); a1[1]+=f8u((x1>>8)&255); a1[2]+=f8u((x1>>16)&255); a1[3]+=f8u(x1>>24);
            a1[4]+=f8u(y1&255); a1[5]+=f8u((y1>>8)&255); a1[6]+=f8u((y1>>16)&255); a1[7]+=f8u(y1>>24);
        }
        #pragma unroll
        for (int k = 0; k < 8; k++) s[k] += a0[k] + a1[k];
    }
    for (; e + 4 <= r1; e += 4) {
        int c0 = col[e], c1 = col[e + 1], c2 = col[e + 2], c3 = col[e + 3];
        uint2 u0 = *(const uint2*)(gsrc + (((size_t)c0) << 6) + fo);
        uint2 u1 = *(const uint2*)(gsrc + (((size_t)c1) << 6) + fo);
        uint2 u2 = *(const uint2*)(gsrc + (((size_t)c2) << 6) + fo);
        uint2 u3 = *(const uint2*)(gsrc + (((size_t)c3) << 6) + fo);
        #pragma unroll
        for (int k = 0; k < 4; k++) {
            int sh = k * 8;
            s[k]     += (f8u((u0.x>>sh)&255) + f8u((u1.x>>sh)&255)) + (f8u((u2.x>>sh)&255) + f8u((u3.x>>sh)&255));
            s[k + 4] += (f8u((u0.y>>sh)&255) + f8u((u1.y>>sh)&255)) + (f8u((u2.y>>sh)&255) + f8u((u3.y>>sh)&255));
        }
    }
    for (; e < r1; ++e) {
        uint2 u = *(const uint2*)(gsrc + (((size_t)col[e]) << 6) + fo);
        s[0]+=f8u(u.x&255); s[1]+=f8u((u.x>>8)&255); s[2]+=f8u((u.x>>16)&255); s[3]+=f8u(u.x>>24);
        s[4]+=f8u(u.y&255); s[5]+=f8u((u.y>>8)&255); s[6]+=f8u((u.y>>16)&255); s[7]+=f8u(u.y>>24);
    }
    if (valid) {
        float dvn = dinv[node];
        uint4 w;
        w.x = (unsigned)f2b(dvn * s[0]) | ((unsigned)f2b(dvn * s[1]) << 16);
        w.y = (unsigned)f2b(dvn * s[2]) | ((unsigned)f2b(dvn * s[3]) << 16);
        w.z = (unsigned)f2b(dvn * s[4]) | ((unsigned)f2b(dvn * s[5]) << 16);
        w.w = (unsigned)f2b(dvn * s[6]) | ((unsigned)f2b(dvn * s[7]) << 16);
        *(uint4*)(gout + (((size_t)node) << 6) + (size_t)(li * 8)) = w;
    }
}

// ---- gemm2s: thread-per-row t@W2 + b2, in-register log_softmax ----

__global__ __launch_bounds__(256) void k_gemm2s(
    const unsigned short* __restrict__ t, const float* __restrict__ W2,
    const float* __restrict__ b2, float* __restrict__ out, int N) {
    __shared__ unsigned short Xs[256 * 72];
    __shared__ float W2s[64 * 40];
    __shared__ float b2s[40];
    int tid = threadIdx.x;
    int row0 = blockIdx.x * 256;
    for (int i = tid; i < 640; i += 256)
        ((float4*)W2s)[i] = ((const float4*)W2)[i];
    if (tid < 40) b2s[tid] = b2[tid];
    for (int c = tid; c < 2048; c += 256) {
        int r = c >> 3, j = c & 7;
        int gr = row0 + r;
        uint4 v = make_uint4(0u, 0u, 0u, 0u);
        if (gr < N) v = *(const uint4*)(t + (((size_t)gr) << 6) + j * 8);
        *(uint4*)(Xs + r * 72 + j * 8) = v;
    }
    __syncthreads();
    int row = row0 + tid;
    if (row >= N) return;
    float acc[40];
    #pragma unroll
    for (int c = 0; c < 40; c++) acc[c] = b2s[c];
    const unsigned short* xr = Xs + tid * 72;
    for (int k = 0; k < 64; k++) {
        float x = bfu(xr[k]);
        #pragma unroll
        for (int j = 0; j < 10; j++) {
            float4 w = ((const float4*)(W2s + k * 40))[j];
            acc[4 * j + 0] += x * w.x;
            acc[4 * j + 1] += x * w.y;
            acc[4 * j + 2] += x * w.z;
            acc[4 * j + 3] += x * w.w;
        }
    }
    float m = acc[0];
    #pragma unroll
    for (int c = 1; c < 40; c++) m = fmaxf(m, acc[c]);
    float p = 0.f;
    #pragma unroll
    for (int c = 0; c < 40; c++) p += __expf(acc[c] - m);
    float l = __logf(p) + m;
    float* orow = out + (size_t)row * 40;
    #pragma unroll
    for (int j = 0; j < 10; j++) {
        float4 ov;
        ov.x = acc[4 * j + 0] - l;
        ov.y = acc[4 * j + 1] - l;
        ov.z = acc[4 * j + 2] - l;
        ov.w = acc[4 * j + 3] - l;
        *(float4*)(orow + 4 * j) = ov;
    }
}

// ---------------- launch ----------------

extern "C" void kernel_launch(void* const* d_in, const int* in_sizes, int n_in,
                              void* d_out, int out_size, void* d_ws, size_t ws_size,
                              hipStream_t stream) {
    const float* x  = (const float*)d_in[0];
    const int*   ei = (const int*)d_in[1];
    const float* W1 = (const float*)d_in[2];
    const float* b1 = (const float*)d_in[3];
    const float* W2 = (const float*)d_in[4];
    const float* b2 = (const float*)d_in[5];
    float* out = (float*)d_out;

    const int N = in_sizes[0] / 128;
    const int E = in_sizes[1] / 2;
    const int B = (N + NPB - 1) >> NPB_SHIFT;
    const int* src = ei;
    const int* dst = ei + E;

    char* w = (char*)d_ws;
    size_t off = 0;
    auto alloc = [&](size_t bytes) -> char* {
        char* p = w + off;
        off += (bytes + 255) & ~(size_t)255;
        return p;
    };
    int*   bcnt   = (int*)alloc((size_t)(B + 1) * 4);
    int*   bstart = (int*)alloc((size_t)(B + 1) * 4);
    int*   cursor = (int*)alloc((size_t)B * 4);
    int*   rowptr = (int*)alloc((size_t)(N + 1) * 4);
    float* dinv   = (float*)alloc((size_t)N * 4);
    int*   col    = (int*)alloc((size_t)E * 4 + 256);
    // sh: pairs (E*4B) during build; then g1 fp8 (N*64*1B)
    size_t shbytes = (size_t)E * 4 > (size_t)N * 64 ? (size_t)E * 4 : (size_t)N * 64;
    char*  sh     = alloc(shbytes);
    unsigned char*  q = (unsigned char*)alloc((size_t)N * 64);
    unsigned short* t = (unsigned short*)alloc((size_t)N * 64 * 2);
    unsigned* pairs  = (unsigned*)sh;
    unsigned char* g1 = (unsigned char*)sh;    // pairs dead after k_p2

    k_zeroB<<<1, 256, 0, stream>>>(bcnt, B);
    k_p1count<<<256, 256, 0, stream>>>(dst, E, B, bcnt);
    k_scanB<<<1, 256, 0, stream>>>(bcnt, B, E, bstart, cursor);
    int nch = (E + P1C - 1) / P1C;
    k_p1place<<<nch, 256, 0, stream>>>(src, dst, E, B, cursor, pairs);
    k_p2<<<B, 512, 0, stream>>>(pairs, bstart, rowptr, dinv, col, N, E);

    int aggblocks = (N + 31) / 32;   // 8 nodes/wave x 4 waves/block

    // layer 1: g1 = fp8(dinv*(x@W1)) [MFMA]; q = fp8(dinv*relu(dinv*(sum g1)+b1))
    k_gemm1m<<<(N + 127) / 128, 256, 0, stream>>>(x, W1, dinv, g1, N);
    k_agg1f8<<<aggblocks, 256, 0, stream>>>(g1, rowptr, col, dinv, b1, q, N);

    // layer 2 (commuted): t = bf16(dinv*(sum q)); out = log_softmax(t@W2 + b2)
    k_agg2f8<<<aggblocks, 256, 0, stream>>>(q, rowptr, col, dinv, t, N);
    k_gemm2s<<<(N + 255) / 256, 256, 0, stream>>>(t, W2, b2, out, N);
}

// Round 25
// 163.020 us; speedup vs baseline: 1.0395x; 1.0395x over previous
//
#include <hip/hip_runtime.h>
#include <hip/hip_bf16.h>
#include <hip/hip_fp8.h>
#include <math.h>

typedef long long i64;
typedef __attribute__((ext_vector_type(8))) short short8v;
typedef __attribute__((ext_vector_type(4))) float f32x4;

__device__ __forceinline__ float bfu(unsigned short u) {
    union { unsigned int i; float f; } v; v.i = ((unsigned)u) << 16; return v.f;
}
__device__ __forceinline__ unsigned short f2b(float f) {
    __hip_bfloat16 h = __float2bfloat16(f);
    return *reinterpret_cast<unsigned short*>(&h);
}
__device__ __forceinline__ float f8u(unsigned char u) {
    __hip_fp8_e4m3 h; h.__x = u; return (float)h;
}
__device__ __forceinline__ unsigned char f2f8(float f) {
    __hip_fp8_e4m3 h(f); return h.__x;
}

// ================= CSR build: 2-phase radix partition by dst =================
// pairs packed: src (bits 0-16) | dst-local (bits 17-25)  [4B/edge]
#define NPB_SHIFT 9
#define NPB 512
#define LCAP 16384
#define P1C 8192

__global__ void k_zeroB(int* __restrict__ bcnt, int B) {
    int t = threadIdx.x;
    if (t <= B) bcnt[t] = 0;
}

__global__ __launch_bounds__(256) void k_p1count(
    const int* __restrict__ dst, int E, int B, int* __restrict__ bcnt) {
    __shared__ int lb[256];
    int t = threadIdx.x;
    lb[t] = 0; __syncthreads();
    int cpb = (E + gridDim.x - 1) / gridDim.x;
    int s0 = blockIdx.x * cpb, s1 = min(E, s0 + cpb);
    for (int i = s0 + t; i < s1; i += 256)
        atomicAdd(&lb[dst[i] >> NPB_SHIFT], 1);
    __syncthreads();
    if (t < B && lb[t]) atomicAdd(&bcnt[t], lb[t]);
}

__global__ void k_scanB(const int* __restrict__ bcnt, int B, int E,
                        int* __restrict__ bstart, int* __restrict__ cursor) {
    __shared__ int s[256];
    int t = threadIdx.x;
    int v = (t < B) ? bcnt[t] : 0;
    s[t] = v; __syncthreads();
    for (int off = 1; off < 256; off <<= 1) {
        int u = (t >= off) ? s[t - off] : 0;
        __syncthreads();
        s[t] += u;
        __syncthreads();
    }
    int excl = s[t] - v;
    if (t < B) { bstart[t] = excl; cursor[t] = excl; }
    if (t == 0) bstart[B] = E;
}

__global__ __launch_bounds__(256) void k_p1place(
    const int* __restrict__ src, const int* __restrict__ dst, int E, int B,
    int* __restrict__ cursor, unsigned* __restrict__ pairs) {
    __shared__ unsigned ls_p[P1C];
    __shared__ unsigned char ls_b[P1C];
    __shared__ int lb[256];
    __shared__ int lbase[256];
    int t = threadIdx.x;
    int s0 = blockIdx.x * P1C, s1 = min(E, s0 + P1C), n = s1 - s0;
    lb[t] = 0; __syncthreads();
    for (int i = t; i < n; i += 256) {
        int d = dst[s0 + i];
        int s = src[s0 + i];
        int bkt = d >> NPB_SHIFT;
        ls_p[i] = (unsigned)s | ((unsigned)(d & (NPB - 1)) << 17);
        ls_b[i] = (unsigned char)bkt;
        atomicAdd(&lb[bkt], 1);
    }
    __syncthreads();
    if (t < B && lb[t]) lbase[t] = atomicAdd(&cursor[t], lb[t]);
    __syncthreads();
    lb[t] = 0; __syncthreads();
    for (int i = t; i < n; i += 256) {
        int bkt = ls_b[i];
        int slot = atomicAdd(&lb[bkt], 1);
        pairs[lbase[bkt] + slot] = ls_p[i];
    }
}

__global__ __launch_bounds__(512) void k_p2(
    const unsigned* __restrict__ pairs, const int* __restrict__ bstart,
    int* __restrict__ rowptr, float* __restrict__ dinv,
    int* __restrict__ col, int N, int E) {
    __shared__ int lcnt[NPB];
    __shared__ int lscan[NPB];
    __shared__ int lcol[LCAP];
    int b = blockIdx.x, t = threadIdx.x;
    int lo = b << NPB_SHIFT, hi = min(N, lo + NPB), nn = hi - lo;
    int e0 = bstart[b], e1 = bstart[b + 1];
    lcnt[t] = 0; __syncthreads();
    for (int i = e0 + t; i < e1; i += 512)
        atomicAdd(&lcnt[(int)(pairs[i] >> 17)], 1);
    __syncthreads();
    int myc = (t < nn) ? lcnt[t] : 0;
    lscan[t] = myc; __syncthreads();
    for (int off = 1; off < 512; off <<= 1) {
        int u = (t >= off) ? lscan[t - off] : 0;
        __syncthreads();
        lscan[t] += u;
        __syncthreads();
    }
    if (t < nn) {
        rowptr[lo + t] = e0 + lscan[t] - myc;
        dinv[lo + t] = rsqrtf((float)(myc + 1));   // +1 self-loop
    }
    if (t == 0 && hi == N) rowptr[N] = E;
    __syncthreads();
    lscan[t] -= myc;
    lcnt[t] = 0;
    __syncthreads();
    for (int i = e0 + t; i < e1; i += 512) {
        unsigned p = pairs[i];
        int n = (int)(p >> 17);
        int slot = atomicAdd(&lcnt[n], 1);
        int idx = lscan[n] + slot;
        if (idx < LCAP) lcol[idx] = (int)(p & 0x1FFFFu);
    }
    __syncthreads();
    int cnt = e1 - e0;
    for (int i = t; i < cnt; i += 512) col[e0 + i] = lcol[i];
}

// ------- GEMM1 (MFMA bf16): g1[r][c] = fp8e4m3( dinv[r] * (x @ W1)[r][c] ) -------

__global__ __launch_bounds__(256) void k_gemm1m(
    const float* __restrict__ X, const float* __restrict__ W,
    const float* __restrict__ dinv, unsigned char* __restrict__ out, int N) {
    __shared__ unsigned short Xs[128 * 128];   // 32 KB
    __shared__ unsigned short Wt[64 * 128];    // 16 KB (W^T)
    int tid = threadIdx.x;
    int row0 = blockIdx.x << 7;

    for (int i = tid; i < 2048; i += 256) {
        float4 v = *(const float4*)(W + i * 4);
        int k = (i * 4) >> 6, n = (i * 4) & 63;
        int kb = k * 2;
        *(unsigned short*)((char*)Wt + (n + 0) * 256 + (kb ^ (((n + 0) & 7) << 4))) = f2b(v.x);
        *(unsigned short*)((char*)Wt + (n + 1) * 256 + (kb ^ (((n + 1) & 7) << 4))) = f2b(v.y);
        *(unsigned short*)((char*)Wt + (n + 2) * 256 + (kb ^ (((n + 2) & 7) << 4))) = f2b(v.z);
        *(unsigned short*)((char*)Wt + (n + 3) * 256 + (kb ^ (((n + 3) & 7) << 4))) = f2b(v.w);
    }
    for (int i = tid; i < 4096; i += 256) {
        int r = i >> 5, c4 = i & 31;
        int gr = row0 + r;
        float4 v = make_float4(0.f, 0.f, 0.f, 0.f);
        if (gr < N) v = *(const float4*)(X + (size_t)gr * 128 + c4 * 4);
        ushort4 h;
        h.x = f2b(v.x); h.y = f2b(v.y); h.z = f2b(v.z); h.w = f2b(v.w);
        *(ushort4*)((char*)Xs + r * 256 + ((c4 * 8) ^ ((r & 7) << 4))) = h;
    }
    __syncthreads();

    int wid = tid >> 6, lane = tid & 63;
    int l15 = lane & 15, lg = lane >> 4;
    int wrow = wid * 32;

    f32x4 acc[2][4];
    #pragma unroll
    for (int fr = 0; fr < 2; fr++)
        #pragma unroll
        for (int fc = 0; fc < 4; fc++) acc[fr][fc] = (f32x4){0.f, 0.f, 0.f, 0.f};

    #pragma unroll
    for (int ks = 0; ks < 4; ks++) {
        int kbyte = ks * 64 + lg * 16;
        int ra0 = wrow + l15, ra1 = wrow + 16 + l15;
        short8v a0 = *(short8v*)((char*)Xs + ra0 * 256 + (kbyte ^ ((ra0 & 7) << 4)));
        short8v a1 = *(short8v*)((char*)Xs + ra1 * 256 + (kbyte ^ ((ra1 & 7) << 4)));
        int swb = kbyte ^ ((l15 & 7) << 4);
        short8v b0 = *(short8v*)((char*)Wt + (l15) * 256 + swb);
        short8v b1 = *(short8v*)((char*)Wt + (16 + l15) * 256 + swb);
        short8v b2 = *(short8v*)((char*)Wt + (32 + l15) * 256 + swb);
        short8v b3 = *(short8v*)((char*)Wt + (48 + l15) * 256 + swb);
        acc[0][0] = __builtin_amdgcn_mfma_f32_16x16x32_bf16(a0, b0, acc[0][0], 0, 0, 0);
        acc[0][1] = __builtin_amdgcn_mfma_f32_16x16x32_bf16(a0, b1, acc[0][1], 0, 0, 0);
        acc[0][2] = __builtin_amdgcn_mfma_f32_16x16x32_bf16(a0, b2, acc[0][2], 0, 0, 0);
        acc[0][3] = __builtin_amdgcn_mfma_f32_16x16x32_bf16(a0, b3, acc[0][3], 0, 0, 0);
        acc[1][0] = __builtin_amdgcn_mfma_f32_16x16x32_bf16(a1, b0, acc[1][0], 0, 0, 0);
        acc[1][1] = __builtin_amdgcn_mfma_f32_16x16x32_bf16(a1, b1, acc[1][1], 0, 0, 0);
        acc[1][2] = __builtin_amdgcn_mfma_f32_16x16x32_bf16(a1, b2, acc[1][2], 0, 0, 0);
        acc[1][3] = __builtin_amdgcn_mfma_f32_16x16x32_bf16(a1, b3, acc[1][3], 0, 0, 0);
    }

    float dv[2][4];
    #pragma unroll
    for (int fr = 0; fr < 2; fr++)
        #pragma unroll
        for (int reg = 0; reg < 4; reg++) {
            int grow = row0 + wrow + fr * 16 + lg * 4 + reg;
            dv[fr][reg] = (grow < N) ? dinv[grow] : 0.f;
        }
    #pragma unroll
    for (int fr = 0; fr < 2; fr++)
        #pragma unroll
        for (int fc = 0; fc < 4; fc++)
            #pragma unroll
            for (int reg = 0; reg < 4; reg++) {
                int grow = row0 + wrow + fr * 16 + lg * 4 + reg;
                if (grow < N)
                    out[(size_t)grow * 64 + fc * 16 + l15] = f2f8(acc[fr][fc][reg] * dv[fr][reg]);
            }
}

// ---- Agg layer 1: fp8 gather, 4 nodes/wave (16 lanes x uchar4 = one 64B row).
//      Epilogue writes q as fp8 too (64B rows -> agg2 is 1 line/edge). ----

__global__ __launch_bounds__(256) void k_agg1f8(
    const unsigned char* __restrict__ gsrc, const int* __restrict__ rowptr,
    const int* __restrict__ col, const float* __restrict__ dinv,
    const float* __restrict__ b1, unsigned char* __restrict__ gout, int N) {
    int gw = (int)((blockIdx.x * 256u + threadIdx.x) >> 6);
    int lane = threadIdx.x & 63;
    int li = lane & 15;                         // feature quarter: 4li..4li+3
    int node = gw * 4 + (lane >> 4);
    bool valid = node < N;
    int r0 = 0, r1 = 0;
    if (valid) { r0 = rowptr[node]; r1 = rowptr[node + 1]; }
    size_t fo = (size_t)(li * 4);
    float s0 = 0.f, s1 = 0.f, s2 = 0.f, s3 = 0.f;
    if (valid) {   // self-loop term
        uchar4 u = *(const uchar4*)(gsrc + (((size_t)node) << 6) + fo);
        s0 = f8u(u.x); s1 = f8u(u.y); s2 = f8u(u.z); s3 = f8u(u.w);
    }
    int e = r0;
    for (; e + 16 <= r1; e += 16) {
        int cc[16];
        #pragma unroll
        for (int j = 0; j < 16; j++) cc[j] = col[e + j];
        uchar4 uu[16];
        #pragma unroll
        for (int j = 0; j < 16; j++)
            uu[j] = *(const uchar4*)(gsrc + (((size_t)cc[j]) << 6) + fo);
        float va[16], vb[16], vc[16], vd[16];
        #pragma unroll
        for (int j = 0; j < 16; j++) {
            va[j] = f8u(uu[j].x); vb[j] = f8u(uu[j].y);
            vc[j] = f8u(uu[j].z); vd[j] = f8u(uu[j].w);
        }
        #pragma unroll
        for (int s = 1; s < 16; s <<= 1)
            #pragma unroll
            for (int j = 0; j + s < 16; j += 2 * s) {
                va[j] += va[j + s]; vb[j] += vb[j + s];
                vc[j] += vc[j + s]; vd[j] += vd[j + s];
            }
        s0 += va[0]; s1 += vb[0]; s2 += vc[0]; s3 += vd[0];
    }
    for (; e + 4 <= r1; e += 4) {
        int c0 = col[e], c1 = col[e + 1], c2 = col[e + 2], c3 = col[e + 3];
        uchar4 u0 = *(const uchar4*)(gsrc + (((size_t)c0) << 6) + fo);
        uchar4 u1 = *(const uchar4*)(gsrc + (((size_t)c1) << 6) + fo);
        uchar4 u2 = *(const uchar4*)(gsrc + (((size_t)c2) << 6) + fo);
        uchar4 u3 = *(const uchar4*)(gsrc + (((size_t)c3) << 6) + fo);
        s0 += (f8u(u0.x) + f8u(u1.x)) + (f8u(u2.x) + f8u(u3.x));
        s1 += (f8u(u0.y) + f8u(u1.y)) + (f8u(u2.y) + f8u(u3.y));
        s2 += (f8u(u0.z) + f8u(u1.z)) + (f8u(u2.z) + f8u(u3.z));
        s3 += (f8u(u0.w) + f8u(u1.w)) + (f8u(u2.w) + f8u(u3.w));
    }
    for (; e < r1; ++e) {
        uchar4 u = *(const uchar4*)(gsrc + (((size_t)col[e]) << 6) + fo);
        s0 += f8u(u.x); s1 += f8u(u.y); s2 += f8u(u.z); s3 += f8u(u.w);
    }
    if (valid) {
        float dvn = dinv[node];
        float4 bb = *(const float4*)(b1 + li * 4);
        uchar4 w;
        w.x = f2f8(dvn * fmaxf(dvn * s0 + bb.x, 0.f));
        w.y = f2f8(dvn * fmaxf(dvn * s1 + bb.y, 0.f));
        w.z = f2f8(dvn * fmaxf(dvn * s2 + bb.z, 0.f));
        w.w = f2f8(dvn * fmaxf(dvn * s3 + bb.w, 0.f));
        *(uchar4*)(gout + (((size_t)node) << 6) + fo) = w;
    }
}

// ---- Agg layer 2: fp8 gather of q (1 line/edge), t output stays bf16 ----

__global__ __launch_bounds__(256) void k_agg2f8(
    const unsigned char* __restrict__ gsrc, const int* __restrict__ rowptr,
    const int* __restrict__ col, const float* __restrict__ dinv,
    unsigned short* __restrict__ gout, int N) {
    int gw = (int)((blockIdx.x * 256u + threadIdx.x) >> 6);
    int lane = threadIdx.x & 63;
    int li = lane & 15;
    int node = gw * 4 + (lane >> 4);
    bool valid = node < N;
    int r0 = 0, r1 = 0;
    if (valid) { r0 = rowptr[node]; r1 = rowptr[node + 1]; }
    size_t fo = (size_t)(li * 4);
    float s0 = 0.f, s1 = 0.f, s2 = 0.f, s3 = 0.f;
    if (valid) {   // self-loop term
        uchar4 u = *(const uchar4*)(gsrc + (((size_t)node) << 6) + fo);
        s0 = f8u(u.x); s1 = f8u(u.y); s2 = f8u(u.z); s3 = f8u(u.w);
    }
    int e = r0;
    for (; e + 16 <= r1; e += 16) {
        int cc[16];
        #pragma unroll
        for (int j = 0; j < 16; j++) cc[j] = col[e + j];
        uchar4 uu[16];
        #pragma unroll
        for (int j = 0; j < 16; j++)
            uu[j] = *(const uchar4*)(gsrc + (((size_t)cc[j]) << 6) + fo);
        float va[16], vb[16], vc[16], vd[16];
        #pragma unroll
        for (int j = 0; j < 16; j++) {
            va[j] = f8u(uu[j].x); vb[j] = f8u(uu[j].y);
            vc[j] = f8u(uu[j].z); vd[j] = f8u(uu[j].w);
        }
        #pragma unroll
        for (int s = 1; s < 16; s <<= 1)
            #pragma unroll
            for (int j = 0; j + s < 16; j += 2 * s) {
                va[j] += va[j + s]; vb[j] += vb[j + s];
                vc[j] += vc[j + s]; vd[j] += vd[j + s];
            }
        s0 += va[0]; s1 += vb[0]; s2 += vc[0]; s3 += vd[0];
    }
    for (; e + 4 <= r1; e += 4) {
        int c0 = col[e], c1 = col[e + 1], c2 = col[e + 2], c3 = col[e + 3];
        uchar4 u0 = *(const uchar4*)(gsrc + (((size_t)c0) << 6) + fo);
        uchar4 u1 = *(const uchar4*)(gsrc + (((size_t)c1) << 6) + fo);
        uchar4 u2 = *(const uchar4*)(gsrc + (((size_t)c2) << 6) + fo);
        uchar4 u3 = *(const uchar4*)(gsrc + (((size_t)c3) << 6) + fo);
        s0 += (f8u(u0.x) + f8u(u1.x)) + (f8u(u2.x) + f8u(u3.x));
        s1 += (f8u(u0.y) + f8u(u1.y)) + (f8u(u2.y) + f8u(u3.y));
        s2 += (f8u(u0.z) + f8u(u1.z)) + (f8u(u2.z) + f8u(u3.z));
        s3 += (f8u(u0.w) + f8u(u1.w)) + (f8u(u2.w) + f8u(u3.w));
    }
    for (; e < r1; ++e) {
        uchar4 u = *(const uchar4*)(gsrc + (((size_t)col[e]) << 6) + fo);
        s0 += f8u(u.x); s1 += f8u(u.y); s2 += f8u(u.z); s3 += f8u(u.w);
    }
    if (valid) {
        float dvn = dinv[node];
        ushort4 w;
        w.x = f2b(dvn * s0); w.y = f2b(dvn * s1);
        w.z = f2b(dvn * s2); w.w = f2b(dvn * s3);
        *(ushort4*)(gout + (((size_t)node) << 6) + fo) = w;
    }
}

// ---- gemm2s: thread-per-row t@W2 + b2, in-register log_softmax ----

__global__ __launch_bounds__(256) void k_gemm2s(
    const unsigned short* __restrict__ t, const float* __restrict__ W2,
    const float* __restrict__ b2, float* __restrict__ out, int N) {
    __shared__ unsigned short Xs[256 * 72];
    __shared__ float W2s[64 * 40];
    __shared__ float b2s[40];
    int tid = threadIdx.x;
    int row0 = blockIdx.x * 256;
    for (int i = tid; i < 640; i += 256)
        ((float4*)W2s)[i] = ((const float4*)W2)[i];
    if (tid < 40) b2s[tid] = b2[tid];
    for (int c = tid; c < 2048; c += 256) {
        int r = c >> 3, j = c & 7;
        int gr = row0 + r;
        uint4 v = make_uint4(0u, 0u, 0u, 0u);
        if (gr < N) v = *(const uint4*)(t + (((size_t)gr) << 6) + j * 8);
        *(uint4*)(Xs + r * 72 + j * 8) = v;
    }
    __syncthreads();
    int row = row0 + tid;
    if (row >= N) return;
    float acc[40];
    #pragma unroll
    for (int c = 0; c < 40; c++) acc[c] = b2s[c];
    const unsigned short* xr = Xs + tid * 72;
    for (int k = 0; k < 64; k++) {
        float x = bfu(xr[k]);
        #pragma unroll
        for (int j = 0; j < 10; j++) {
            float4 w = ((const float4*)(W2s + k * 40))[j];
            acc[4 * j + 0] += x * w.x;
            acc[4 * j + 1] += x * w.y;
            acc[4 * j + 2] += x * w.z;
            acc[4 * j + 3] += x * w.w;
        }
    }
    float m = acc[0];
    #pragma unroll
    for (int c = 1; c < 40; c++) m = fmaxf(m, acc[c]);
    float p = 0.f;
    #pragma unroll
    for (int c = 0; c < 40; c++) p += __expf(acc[c] - m);
    float l = __logf(p) + m;
    float* orow = out + (size_t)row * 40;
    #pragma unroll
    for (int j = 0; j < 10; j++) {
        float4 ov;
        ov.x = acc[4 * j + 0] - l;
        ov.y = acc[4 * j + 1] - l;
        ov.z = acc[4 * j + 2] - l;
        ov.w = acc[4 * j + 3] - l;
        *(float4*)(orow + 4 * j) = ov;
    }
}

// ---------------- launch ----------------

extern "C" void kernel_launch(void* const* d_in, const int* in_sizes, int n_in,
                              void* d_out, int out_size, void* d_ws, size_t ws_size,
                              hipStream_t stream) {
    const float* x  = (const float*)d_in[0];
    const int*   ei = (const int*)d_in[1];
    const float* W1 = (const float*)d_in[2];
    const float* b1 = (const float*)d_in[3];
    const float* W2 = (const float*)d_in[4];
    const float* b2 = (const float*)d_in[5];
    float* out = (float*)d_out;

    const int N = in_sizes[0] / 128;
    const int E = in_sizes[1] / 2;
    const int B = (N + NPB - 1) >> NPB_SHIFT;
    const int* src = ei;
    const int* dst = ei + E;

    char* w = (char*)d_ws;
    size_t off = 0;
    auto alloc = [&](size_t bytes) -> char* {
        char* p = w + off;
        off += (bytes + 255) & ~(size_t)255;
        return p;
    };
    int*   bcnt   = (int*)alloc((size_t)(B + 1) * 4);
    int*   bstart = (int*)alloc((size_t)(B + 1) * 4);
    int*   cursor = (int*)alloc((size_t)B * 4);
    int*   rowptr = (int*)alloc((size_t)(N + 1) * 4);
    float* dinv   = (float*)alloc((size_t)N * 4);
    int*   col    = (int*)alloc((size_t)E * 4 + 256);
    // sh: pairs (E*4B) during build; then g1 fp8 (N*64*1B)
    size_t shbytes = (size_t)E * 4 > (size_t)N * 64 ? (size_t)E * 4 : (size_t)N * 64;
    char*  sh     = alloc(shbytes);
    unsigned char*  q = (unsigned char*)alloc((size_t)N * 64);
    unsigned short* t = (unsigned short*)alloc((size_t)N * 64 * 2);
    unsigned* pairs  = (unsigned*)sh;
    unsigned char* g1 = (unsigned char*)sh;    // pairs dead after k_p2

    k_zeroB<<<1, 256, 0, stream>>>(bcnt, B);
    k_p1count<<<256, 256, 0, stream>>>(dst, E, B, bcnt);
    k_scanB<<<1, 256, 0, stream>>>(bcnt, B, E, bstart, cursor);
    int nch = (E + P1C - 1) / P1C;
    k_p1place<<<nch, 256, 0, stream>>>(src, dst, E, B, cursor, pairs);
    k_p2<<<B, 512, 0, stream>>>(pairs, bstart, rowptr, dinv, col, N, E);

    int aggblocks = (N + 15) / 16;   // 4 nodes/wave x 4 waves/block

    // layer 1: g1 = fp8(dinv*(x@W1)) [MFMA]; q = fp8(dinv*relu(dinv*(sum g1)+b1))
    k_gemm1m<<<(N + 127) / 128, 256, 0, stream>>>(x, W1, dinv, g1, N);
    k_agg1f8<<<aggblocks, 256, 0, stream>>>(g1, rowptr, col, dinv, b1, q, N);

    // layer 2 (commuted): t = bf16(dinv*(sum q)); out = log_softmax(t@W2 + b2)
    k_agg2f8<<<aggblocks, 256, 0, stream>>>(q, rowptr, col, dinv, t, N);
    k_gemm2s<<<(N + 255) / 256, 256, 0, stream>>>(t, W2, b2, out, N);
}